// Round 11
// baseline (298.648 us; speedup 1.0000x reference)
//
#include <hip/hip_runtime.h>
#include <hip/hip_bf16.h>
#include <hip/hip_fp16.h>

// B=8192, T=512, IN=1, H=20, OUT=1
#define B_TOTAL 8192
#define T_LEN   512
#define H       20
#define NBW     3      // batches per block (3*20=60 lanes/wave; 60-63 dummies -> row 3)
#define XSTR    520    // xs row stride in floats
#define HROWU   12     // h row stride in uints (48B; 10 used = 20 halves)
#define WROWU   12     // packed weight row stride in uints
#define WMATU   (H * WROWU)   // 240 uints per matrix

typedef _Float16 half2v __attribute__((ext_vector_type(2)));

#define FDOT2(a, b, c) __builtin_amdgcn_fdot2((a), (b), (c), false)

// tanh(x) = 1 - 2/(exp2(x*2*log2e)+1)
__device__ __forceinline__ float fast_tanh(float x) {
    float e = __builtin_amdgcn_exp2f(x * 2.885390081777927f);
    return fmaf(-2.0f, __builtin_amdgcn_rcpf(e + 1.0f), 1.0f);
}

__device__ __forceinline__ half2v h2v(unsigned int u) {
    return __builtin_bit_cast(half2v, u);
}

// Load 20 halves (10 packed pairs) from LDS: b128 + b128 + b64.
#define RDH(dst, base) \
    uint4 dst##A = ((const uint4*)(base))[0]; \
    uint4 dst##B = ((const uint4*)(base))[1]; \
    uint2 dst##C = *(const uint2*)(((const unsigned int*)(base)) + 8);

// acc0/acc1 += h . w ; h packed pairs from RDH, w = 10 SCALAR uints wn##0..wn##9.
#define DOTW(acc0, acc1, hv, wn) \
    acc0 = FDOT2(h2v(hv##A.x), h2v(wn##0), acc0); acc1 = FDOT2(h2v(hv##A.y), h2v(wn##1), acc1); \
    acc0 = FDOT2(h2v(hv##A.z), h2v(wn##2), acc0); acc1 = FDOT2(h2v(hv##A.w), h2v(wn##3), acc1); \
    acc0 = FDOT2(h2v(hv##B.x), h2v(wn##4), acc0); acc1 = FDOT2(h2v(hv##B.y), h2v(wn##5), acc1); \
    acc0 = FDOT2(h2v(hv##B.z), h2v(wn##6), acc0); acc1 = FDOT2(h2v(hv##B.w), h2v(wn##7), acc1); \
    acc0 = FDOT2(h2v(hv##C.x), h2v(wn##8), acc0); acc1 = FDOT2(h2v(hv##C.y), h2v(wn##9), acc1);

// Declare 10 scalar uints and fill from a uint4/uint4/uint2 row load.
#define LDW(wn, base) \
    unsigned int wn##0, wn##1, wn##2, wn##3, wn##4, wn##5, wn##6, wn##7, wn##8, wn##9; \
    { uint4 _a = *(const uint4*)(base); \
      uint4 _b = *(const uint4*)((const unsigned int*)(base) + 4); \
      uint2 _c = *(const uint2*)((const unsigned int*)(base) + 8); \
      wn##0=_a.x; wn##1=_a.y; wn##2=_a.z; wn##3=_a.w; \
      wn##4=_b.x; wn##5=_b.y; wn##6=_b.z; wn##7=_b.w; \
      wn##8=_c.x; wn##9=_c.y; }

// ---- prologue: convert 5 HxH f32 matrices to packed-f16 rows in ws ----
__global__ void prep_w(const float* __restrict__ w_hh0, const float* __restrict__ w_ih1,
                       const float* __restrict__ w_hh1, const float* __restrict__ w_ih2,
                       const float* __restrict__ w_hh2, unsigned int* __restrict__ ws)
{
    int i = threadIdx.x;           // 0..127; first 100 = (matrix m, row r)
    if (i < 5 * H) {
        const float* src;
        int m = i / H, r = i - m * H;
        switch (m) {
            case 0: src = w_hh0; break;
            case 1: src = w_ih1; break;
            case 2: src = w_hh1; break;
            case 3: src = w_ih2; break;
            default: src = w_hh2; break;
        }
        const float* p = src + r * H;
        unsigned int* dst = ws + m * WMATU + r * WROWU;
        #pragma unroll
        for (int q = 0; q < 10; ++q) {
            unsigned short lo = __builtin_bit_cast(unsigned short, (_Float16)p[2*q]);
            unsigned short hi = __builtin_bit_cast(unsigned short, (_Float16)p[2*q+1]);
            dst[q] = (unsigned int)lo | ((unsigned int)hi << 16);
        }
        dst[10] = 0u; dst[11] = 0u;
    }
}

// Two waves per block: wave 0 = layers 0+1 (30 weight words), wave 1 = layer 2 + FC
// (20 words). Per-wave register demand ~55 fits the allocator's comfort zone ->
// weights stay resident without pins. h1 double-buffered across the wave boundary;
// one block-uniform __syncthreads per tick.
__global__ __launch_bounds__(128, 4) void rnn_wave(
    const float* __restrict__ x,
    const float* __restrict__ w_ih0,
    const float* __restrict__ b_ih0, const float* __restrict__ b_hh0,
    const float* __restrict__ b_ih1, const float* __restrict__ b_hh1,
    const float* __restrict__ b_ih2, const float* __restrict__ b_hh2,
    const float* __restrict__ fc_w,  const float* __restrict__ fc_b,
    const unsigned int* __restrict__ wpk,   // packed f16 weights (5 matrices)
    float* __restrict__ out)
{
    __shared__ __align__(16) float        xs[4][XSTR];
    __shared__ __align__(16) unsigned int h0s[4][HROWU];        // wave0-private
    __shared__ __align__(16) unsigned int h1s[2][4][HROWU];     // dbuf: A writes, A+B read
    __shared__ __align__(16) unsigned int h2s[4][HROWU];        // wave1-private

    const int tid  = threadIdx.x;
    const int wv   = tid >> 6;         // 0 = layers 0+1, 1 = layer 2
    const int lane = tid & 63;
    const int bb   = lane / H;         // 0..3 (3 = dummy lanes)
    const int j    = lane - bb * H;    // 0..19
    const int gb   = blockIdx.x * NBW + bb;

    // ---- one-time: stage x rows (coalesced float4), zero h state ----
    {
        const int gb0 = blockIdx.x * NBW;
        #pragma unroll
        for (int it = 0; it < 3; ++it) {
            int fidx = (it * 128 + tid) * 4;      // 0..1532 (rows 0..2)
            int row  = fidx >> 9;
            int col  = fidx & 511;
            int grow = gb0 + row;
            if (grow > B_TOTAL - 1) grow = B_TOTAL - 1;
            *(float4*)&xs[row][col] = *(const float4*)(x + (size_t)grow * T_LEN + col);
        }
        for (int i = tid; i < XSTR; i += 128) xs[3][i] = 0.f;
        for (int i = tid; i < 4 * HROWU; i += 128) {
            (&h0s[0][0])[i] = 0u;
            (&h2s[0][0])[i] = 0u;
        }
        for (int i = tid; i < 2 * 4 * HROWU; i += 128)
            (&h1s[0][0][0])[i] = 0u;
    }

    // ---- per-lane weight rows into SHARED locals (union liveness = 30 words) ----
    // wave0: wA=whh0, wB=wih1, wC=whh1 ; wave1: wA=wih2, wB=whh2, wC=dup(whh2, unused)
    const unsigned int* wr = wpk + j * WROWU;
    const int m0 = (wv == 0) ? 0 : 3;
    const int m1 = (wv == 0) ? 1 : 4;
    const int m2 = (wv == 0) ? 2 : 4;
    LDW(wA_, wr + m0 * WMATU)
    LDW(wB_, wr + m1 * WMATU)
    LDW(wC_, wr + m2 * WMATU)

    const float wih0j = w_ih0[j];
    const float biasP = (wv == 0) ? (b_ih0[j] + b_hh0[j]) : (b_ih2[j] + b_hh2[j]);
    const float biasQ = (wv == 0) ? (b_ih1[j] + b_hh1[j]) : 0.f;

    // ---- diagonal pipeline: tick t -> A: h0(t), h1(t-1); B: h2(t-2) ----
    // h1(time) lives in slot time&1. A reads h1(t-2) slot t&1, writes h1(t-1)
    // slot (t&1)^1. B reads h1(t-2) slot t&1. Barrier separates ticks.
    for (int t = 0; t < T_LEN + 2; ++t) {
        __syncthreads();
        if (wv == 0) {
            const bool do0 = (t < T_LEN);
            const bool do1 = (t >= 1) && (t <= T_LEN);
            float t0 = 0.f, t1 = 0.f;
            if (do0 || do1) {
                RDH(h0v, &h0s[bb][0])
                if (do0) {
                    float a0 = fmaf(xs[bb][t & (T_LEN - 1)], wih0j, biasP), a0b = 0.f;
                    DOTW(a0, a0b, h0v, wA_)
                    t0 = fast_tanh(a0 + a0b);
                }
                if (do1) {
                    float a1 = biasQ, a1b = 0.f;
                    DOTW(a1, a1b, h0v, wB_)
                    RDH(h1v, &h1s[t & 1][bb][0])
                    DOTW(a1, a1b, h1v, wC_)
                    t1 = fast_tanh(a1 + a1b);
                }
            }
            if (do0) ((__half*)&h0s[bb][0])[j] = (__half)t0;
            if (do1) ((__half*)&h1s[(t & 1) ^ 1][bb][0])[j] = (__half)t1;
        } else {
            if (t >= 2) {
                RDH(h1v, &h1s[t & 1][bb][0])
                float a2 = biasP, a2b = 0.f;
                DOTW(a2, a2b, h1v, wA_)
                RDH(h2v, &h2s[bb][0])
                DOTW(a2, a2b, h2v, wB_)
                float t2 = fast_tanh(a2 + a2b);
                ((__half*)&h2s[bb][0])[j] = (__half)t2;
            }
        }
    }

    // ---- FC epilogue (wave 1 owns h2) ----
    if (wv == 1 && j == 0 && bb < NBW && gb < B_TOTAL) {
        float acc = fc_b[0];
        const __half* hp = (const __half*)&h2s[bb][0];
        #pragma unroll
        for (int k = 0; k < H; ++k)
            acc = fmaf((float)hp[k], fc_w[k], acc);
        out[gb] = acc;
    }
}

extern "C" void kernel_launch(void* const* d_in, const int* in_sizes, int n_in,
                              void* d_out, int out_size, void* d_ws, size_t ws_size,
                              hipStream_t stream) {
    const float* x     = (const float*)d_in[0];
    const float* w_ih0 = (const float*)d_in[1];
    const float* w_hh0 = (const float*)d_in[2];
    const float* b_ih0 = (const float*)d_in[3];
    const float* b_hh0 = (const float*)d_in[4];
    const float* w_ih1 = (const float*)d_in[5];
    const float* w_hh1 = (const float*)d_in[6];
    const float* b_ih1 = (const float*)d_in[7];
    const float* b_hh1 = (const float*)d_in[8];
    const float* w_ih2 = (const float*)d_in[9];
    const float* w_hh2 = (const float*)d_in[10];
    const float* b_ih2 = (const float*)d_in[11];
    const float* b_hh2 = (const float*)d_in[12];
    const float* fc_w  = (const float*)d_in[13];
    const float* fc_b  = (const float*)d_in[14];
    float* out = (float*)d_out;
    unsigned int* wpk = (unsigned int*)d_ws;   // needs 5*240*4 = 4800 B

    prep_w<<<1, 128, 0, stream>>>(w_hh0, w_ih1, w_hh1, w_ih2, w_hh2, wpk);

    const int nblocks = (B_TOTAL + NBW - 1) / NBW;   // 2731
    rnn_wave<<<nblocks, 128, 0, stream>>>(
        x, w_ih0, b_ih0, b_hh0, b_ih1, b_hh1, b_ih2, b_hh2,
        fc_w, fc_b, wpk, out);
}